// Round 11
// baseline (2360.916 us; speedup 1.0000x reference)
//
#include <hip/hip_runtime.h>
#include <hip/hip_bf16.h>

typedef __bf16 bf16;
typedef __bf16 bf16x8 __attribute__((ext_vector_type(8)));
typedef __bf16 bf16x4 __attribute__((ext_vector_type(4)));
typedef float f32x4 __attribute__((ext_vector_type(4)));
typedef float f32x16 __attribute__((ext_vector_type(16)));

#define T_SEQ 80
#define NB 128
#define NT 512
#define U 1024
#define U3 3072

// ws byte offsets
#define WT_OFF   0ull                  // 3*3072*1024*2 = 18874368
#define WXT_OFF  18874368ull           // 3072*128*2    = 786432
#define XG_OFF   19660800ull           // 80*128*128*2  = 2621440
#define GX1_OFF  22282240ull           // 80*3072*128*2 = 62914560
#define H0B_OFF  85196800ull           // 81 * 128*1024*2 = 21233664 (deep buffers)
#define H1B_OFF  106430464ull          // 21233664
#define CNT_OFF  127664128ull          // barrier counters (2048 B)
#define WS_NEED  127666176ull

#define HBUF_ELEMS 131072ull           // 128*1024 bf16 per h buffer

#define LDS_SX_OFF   147456                 // after 3*24*1024 bf16 weights
#define LDS_RED_OFF  (147456 + 4*64*24*2)   // after SxL[4][64][24] bf16 = 12288
#define LDS_BYTES    (LDS_RED_OFF + 64)     // = 159808 <= 163840

__device__ __forceinline__ float sigmoidf_(float x) { return 1.f / (1.f + __expf(-x)); }

__global__ void k_embed(const int* __restrict__ tok, const float* __restrict__ E,
                        bf16* __restrict__ Xg) {
  int idx = blockIdx.x * 256 + threadIdx.x;   // over 80*128*128, layout [t][b][k]
  int k = idx & 127;
  int bt = idx >> 7;
  int b = bt & 127;
  int t = bt >> 7;
  float v = 0.f;
  if (k < 100) v = E[(size_t)tok[b * 80 + t] * 100 + k];
  Xg[idx] = (bf16)v;
}

__global__ void k_trans(const float* __restrict__ Wh1, const float* __restrict__ Wx2,
                        const float* __restrict__ Wh2, bf16* __restrict__ WT) {
  __shared__ float tile[32][33];
  const float* src = (blockIdx.z == 0) ? Wh1 : (blockIdx.z == 1) ? Wx2 : Wh2;
  int cb = blockIdx.x * 32, kb = blockIdx.y * 32;
  int tx = threadIdx.x, ty = threadIdx.y;
  for (int i = ty; i < 32; i += 8) tile[i][tx] = src[(size_t)(kb + i) * U3 + cb + tx];
  __syncthreads();
  bf16* dst = WT + (size_t)blockIdx.z * U3 * U;  // [col][k] bf16
  for (int i = ty; i < 32; i += 8) dst[(size_t)(cb + i) * U + kb + tx] = (bf16)tile[tx][i];
}

__global__ void k_wxt(const float* __restrict__ Wx1, bf16* __restrict__ WXT) {
  __shared__ float tile[32][33];
  int cb = blockIdx.x * 32, kb = blockIdx.y * 32;
  int tx = threadIdx.x, ty = threadIdx.y;
  for (int i = ty; i < 32; i += 8) {
    int k = kb + i;
    tile[i][tx] = (k < 100) ? Wx1[(size_t)k * U3 + cb + tx] : 0.f;
  }
  __syncthreads();
  for (int i = ty; i < 32; i += 8) WXT[(size_t)(cb + i) * 128 + kb + tx] = (bf16)tile[tx][i];
}

// GX1[t][col][b] = (x_t @ Wx1 + bx1), bf16, col-major over batch
__global__ __launch_bounds__(256) void k_gx1(const bf16* __restrict__ Xg,
                                             const bf16* __restrict__ WXT,
                                             const float* __restrict__ bx1,
                                             bf16* __restrict__ GX1) {
  int mb = blockIdx.x * 64, nb = blockIdx.y * 64;
  int w = threadIdx.x >> 6, l = threadIdx.x & 63;
  int lr = l & 15, lq = l >> 4;
  int rowA = mb + w * 16 + lr;                 // m = t*128 + b
  int tA = rowA >> 7, bA = rowA & 127;
  const bf16* aptr = Xg + ((size_t)tA * 128 + bA) * 128 + lq * 8;
  f32x4 acc[4] = {};
  #pragma unroll
  for (int ks = 0; ks < 4; ++ks) {
    bf16x8 a = *(const bf16x8*)(aptr + ks * 32);
    #pragma unroll
    for (int nt = 0; nt < 4; ++nt) {
      int col = nb + nt * 16 + lr;
      bf16x8 b = *(const bf16x8*)(WXT + (size_t)col * 128 + ks * 32 + lq * 8);
      acc[nt] = __builtin_amdgcn_mfma_f32_16x16x32_bf16(a, b, acc[nt], 0, 0, 0);
    }
  }
  int m0 = mb + w * 16 + lq * 4;
  int t0 = m0 >> 7, b0 = m0 & 127;
  #pragma unroll
  for (int nt = 0; nt < 4; ++nt) {
    int col = nb + nt * 16 + lr;
    float bias = bx1[col];
    bf16x4 o;
    #pragma unroll
    for (int j = 0; j < 4; ++j) o[j] = (bf16)(acc[nt][j] + bias);
    *(bf16x4*)(GX1 + ((size_t)t0 * U3 + col) * 128 + b0) = o;
  }
}

// B-fragment for 32x32x16: lane supplies col (l&31 -> slot scol), k=16s + hi*8..+8.
// Slot data is 4-bit XOR-swizzled at 16B-granule level: granule m stored at m^(scol&15).
__device__ __forceinline__ bf16x8 ldsw32(const bf16* Wlds, int mat, int scol, int m) {
  return *(const bf16x8*)(Wlds + (((mat * 24 + scol) << 10) + ((m ^ (scol & 15)) << 3)));
}

// Packed-pair h store: lanes c (even) and c+1 hold adjacent columns, same row.
// Agent-scope relaxed atomic store -> data lands at the coherence point (IF).
__device__ __forceinline__ void st_pair(bf16* dst_even, int c, float h) {
  bf16 hb16 = (bf16)h;
  unsigned hb = (unsigned)__builtin_bit_cast(unsigned short, hb16);
  unsigned pb = (unsigned)__shfl_xor((int)hb, 1) & 0xffffu;
  if (!(c & 1)) {
    unsigned v = hb | (pb << 16);
    __hip_atomic_store((unsigned*)dst_even, v, __ATOMIC_RELAXED, __HIP_MEMORY_SCOPE_AGENT);
  }
}

// Fence-free tree barrier (measured ~1.67 us/barrier at 128 blocks).
__device__ void gridbar(int* cnt, int i) {
  __syncthreads();
  if (threadIdx.x == 0) {
    int* gc   = cnt + (blockIdx.x & 7) * 32;   // 128B apart
    int* root = cnt + 256;
    int* go   = cnt + 288;
    int old = __hip_atomic_fetch_add(gc, 1, __ATOMIC_RELAXED, __HIP_MEMORY_SCOPE_AGENT);
    if (old == 16 * (i + 1) - 1) {             // group leader this iteration
      int r = __hip_atomic_fetch_add(root, 1, __ATOMIC_RELAXED, __HIP_MEMORY_SCOPE_AGENT);
      if (r == 8 * (i + 1) - 1)
        __hip_atomic_store(go, i + 1, __ATOMIC_RELAXED, __HIP_MEMORY_SCOPE_AGENT);
    }
    while (__hip_atomic_load(go, __ATOMIC_RELAXED, __HIP_MEMORY_SCOPE_AGENT) < i + 1)
      __builtin_amdgcn_s_sleep(4);
  }
  __syncthreads();
}

// NT=512, 32x32x16 MFMA. Waves 0-3 ("light"): rows 32w; gh1 (full K) + gx2 (k<512),
// sharing A-fragments; own the h0 update. Waves 4-7 ("heavy"): rows 32(w-4);
// gx2 (k>=512) + gh2 (full K); combine gx2 halves via SxL; own the h1 update.
// B-tile: cols 0-7=z, 8-15=r, 16-23=n, 24-31 mirror z (broadcast, output ignored).
__global__ __launch_bounds__(NT, 2) void k_main(
    const bf16* __restrict__ WT, const bf16* __restrict__ GX1,
    bf16* __restrict__ h0b, bf16* __restrict__ h1b, int* __restrict__ cnt,
    const float* __restrict__ bh1, const float* __restrict__ bx2,
    const float* __restrict__ bh2, const float* __restrict__ Wf,
    const float* __restrict__ bfp, float* __restrict__ out) {
  extern __shared__ char lds[];
  bf16* Wlds = (bf16*)lds;
  bf16* SxL  = (bf16*)(lds + LDS_SX_OFF);     // [4 tiles][64 lanes][24] gx2 low-K partial
  float* red = (float*)(lds + LDS_RED_OFF);

  const int tid = threadIdx.x;
  const int w = tid >> 6, l = tid & 63;
  const int c = l & 31, hi = l >> 5;
  const int c0 = blockIdx.x * 8;              // this block's h-column base
  const int scol = (c < 24) ? c : (c - 24);

  // global column this lane's B-slot corresponds to (mirror lanes -> z again)
  int col_g;
  if (c < 8)       col_g = c0 + c;
  else if (c < 16) col_g = U + c0 + (c - 8);
  else if (c < 24) col_g = 2 * U + c0 + (c - 16);
  else             col_g = c0 + (c - 24);

  // ---- stage 3x24 weight columns into LDS (bf16, k-contiguous, XOR-swizzled) ----
  for (int u = tid; u < 9216; u += NT) {      // 72 slots * 128 granules
    int chunk = u & 127;
    int s72 = u >> 7;
    int mat = s72 / 24, s = s72 - mat * 24;
    int gcol = c0 + (s & 7) + ((s >> 3) << 10);   // s<8:z  8..15:r(+1024)  16..23:n(+2048)
    bf16x8 v = *(const bf16x8*)(WT + ((size_t)mat * U3 + gcol) * U + chunk * 8);
    *(bf16x8*)(Wlds + ((size_t)s72 << 10) + ((chunk ^ (s & 15)) << 3)) = v;
  }
  __syncthreads();

  // ---- per-lane biases (constant across iters) ----
  const float b1c  = bh1[col_g];
  const float bx2c = bx2[col_g];
  const float bh2c = bh2[col_g];

  float hm[16];                               // fp32 master state (cols c<8 lanes only)
  #pragma unroll
  for (int q = 0; q < 16; ++q) hm[q] = 0.f;

  for (int i = 0; i <= T_SEQ; ++i) {
    // deep buffers: iter i reads h0b[i], h1b[i-1]; writes h0b[i+1], h1b[i].
    const bf16* h0r = h0b + (size_t)i * HBUF_ELEMS;
    const bf16* h1r = h1b + (size_t)(i > 0 ? i - 1 : 0) * HBUF_ELEMS;
    bf16* h0w = h0b + (size_t)(i + 1) * HBUF_ELEMS;
    bf16* h1w = h1b + (size_t)i * HBUF_ELEMS;

    f32x16 hacc2 = {}, hacc3 = {};            // heavy accs live across the mid-sync

    if (w < 4) {
      // ===== light: gh1 full K + gx2 low half-K (shared A = h0 rows 32w) =====
      f32x16 acc1 = {}, acc2 = {};
      const bf16* A0 = h0r + (size_t)(w * 32 + c) * U + hi * 8;
      #pragma unroll 8
      for (int s = 0; s < 32; ++s) {
        bf16x8 A = *(const bf16x8*)(A0 + s * 16);
        bf16x8 B1 = ldsw32(Wlds, 0, scol, 2 * s + hi);
        bf16x8 B2 = ldsw32(Wlds, 1, scol, 2 * s + hi);
        acc1 = __builtin_amdgcn_mfma_f32_32x32x16_bf16(A, B1, acc1, 0, 0, 0);
        acc2 = __builtin_amdgcn_mfma_f32_32x32x16_bf16(A, B2, acc2, 0, 0, 0);
      }
      #pragma unroll 8
      for (int s = 32; s < 64; ++s) {
        bf16x8 A = *(const bf16x8*)(A0 + s * 16);
        bf16x8 B1 = ldsw32(Wlds, 0, scol, 2 * s + hi);
        acc1 = __builtin_amdgcn_mfma_f32_32x32x16_bf16(A, B1, acc1, 0, 0, 0);
      }
      // deposit gx2 low-K partial (bf16) for the paired heavy wave
      {
        bf16* sx = SxL + (size_t)(w * 64 + l) * 24;
        #pragma unroll
        for (int m = 0; m < 4; ++m) {
          bf16x4 t;
          #pragma unroll
          for (int j = 0; j < 4; ++j) t[j] = (bf16)acc2[4 * m + j];
          *(bf16x4*)(sx + 4 * m) = t;
        }
      }
      // h0 update: H0[i] = GRU1(H0[i-1], x[i])
      if (i < T_SEQ) {
        float g[16], p[16], q[16];
        const bf16* gx = GX1 + (size_t)i * U3 * 128 + (size_t)col_g * 128 + w * 32 + 4 * hi;
        #pragma unroll
        for (int m = 0; m < 4; ++m) {
          bf16x4 t = *(const bf16x4*)(gx + 8 * m);
          #pragma unroll
          for (int j = 0; j < 4; ++j) g[4 * m + j] = (float)t[j];
        }
        #pragma unroll
        for (int r = 0; r < 16; ++r) { p[r] = acc1[r] + b1c; q[r] = p[r] + g[r]; }
        float rr[16], gn[16], pn[16];
        #pragma unroll
        for (int r = 0; r < 16; ++r) {
          rr[r] = __shfl_xor(q[r], 8);        // r-gate preact (col c+8)
          gn[r] = __shfl_xor(g[r], 16);       // gx1 n-part   (col c+16)
          pn[r] = __shfl_xor(p[r], 16);       // gh1 n-part   (col c+16)
        }
        if (c < 8) {
          #pragma unroll
          for (int r = 0; r < 16; ++r) {
            float z  = sigmoidf_(q[r]);
            float rv = sigmoidf_(rr[r]);
            float nn = tanhf(gn[r] + rv * pn[r]);
            float h  = z * hm[r] + (1.f - z) * nn;
            hm[r] = h;
            int row = w * 32 + (r & 3) + 8 * (r >> 2) + 4 * hi;
            st_pair(h0w + (size_t)row * U + c0 + (c & ~1), c, h);
          }
        }
      }
    } else if (i > 0) {
      // ===== heavy: gh2 full K + gx2 high half-K (rows 32(w-4)) =====
      const int wt = w - 4;
      const bf16* A1 = h1r + (size_t)(wt * 32 + c) * U + hi * 8;
      const bf16* A0 = h0r + (size_t)(wt * 32 + c) * U + hi * 8;
      #pragma unroll 8
      for (int s = 0; s < 32; ++s) {
        bf16x8 Af = *(const bf16x8*)(A1 + s * 16);
        bf16x8 B3 = ldsw32(Wlds, 2, scol, 2 * s + hi);
        hacc3 = __builtin_amdgcn_mfma_f32_32x32x16_bf16(Af, B3, hacc3, 0, 0, 0);
      }
      #pragma unroll 8
      for (int s = 32; s < 64; ++s) {
        bf16x8 Af0 = *(const bf16x8*)(A0 + s * 16);
        bf16x8 B2 = ldsw32(Wlds, 1, scol, 2 * s + hi);
        hacc2 = __builtin_amdgcn_mfma_f32_32x32x16_bf16(Af0, B2, hacc2, 0, 0, 0);
        bf16x8 Af1 = *(const bf16x8*)(A1 + s * 16);
        bf16x8 B3 = ldsw32(Wlds, 2, scol, 2 * s + hi);
        hacc3 = __builtin_amdgcn_mfma_f32_32x32x16_bf16(Af1, B3, hacc3, 0, 0, 0);
      }
    }
    __syncthreads();   // SxL (gx2 low-K) visible to heavy waves
    if (w >= 4 && i > 0) {
      // h1 update: H1 = GRU2(H1, H0[i-1])
      const int wt = w - 4;
      float p2[16], p3[16], q[16];
      {
        const bf16* sx = SxL + (size_t)(wt * 64 + l) * 24;
        #pragma unroll
        for (int m = 0; m < 4; ++m) {
          bf16x4 t = *(const bf16x4*)(sx + 4 * m);
          #pragma unroll
          for (int j = 0; j < 4; ++j) p2[4 * m + j] = (float)t[j];
        }
      }
      #pragma unroll
      for (int r = 0; r < 16; ++r) {
        p2[r] = p2[r] + hacc2[r] + bx2c;      // gx2 total + bx2
        p3[r] = hacc3[r] + bh2c;              // gh2 + bh2
        q[r]  = p2[r] + p3[r];
      }
      float rr[16], xn[16], hn[16];
      #pragma unroll
      for (int r = 0; r < 16; ++r) {
        rr[r] = __shfl_xor(q[r], 8);
        xn[r] = __shfl_xor(p2[r], 16);
        hn[r] = __shfl_xor(p3[r], 16);
      }
      if (c < 8) {
        #pragma unroll
        for (int r = 0; r < 16; ++r) {
          float z  = sigmoidf_(q[r]);
          float rv = sigmoidf_(rr[r]);
          float nn = tanhf(xn[r] + rv * hn[r]);
          float h  = z * hm[r] + (1.f - z) * nn;
          hm[r] = h;
          int row = wt * 32 + (r & 3) + 8 * (r >> 2) + 4 * hi;
          st_pair(h1w + (size_t)row * U + c0 + (c & ~1), c, h);
        }
      }
    }
    gridbar(cnt, i);
  }

  // ---- final dense head: out[b] = sigmoid(H1[79] . Wf + bf), block b ----
  {
    const bf16* h1f = h1b + (size_t)T_SEQ * HBUF_ELEMS + (size_t)blockIdx.x * U;
    float part = 0.f;
    if (tid < 256) {
      int k0 = tid * 4;
      bf16x4 hv = *(const bf16x4*)(h1f + k0);
      #pragma unroll
      for (int j = 0; j < 4; ++j) part += (float)hv[j] * Wf[k0 + j];
    }
    #pragma unroll
    for (int off = 32; off > 0; off >>= 1) part += __shfl_down(part, off);
    if (l == 0) red[w] = part;
    __syncthreads();
    if (tid == 0) {
      float s = bfp[0];
      #pragma unroll
      for (int q = 0; q < 8; ++q) s += red[q];
      out[blockIdx.x] = sigmoidf_(s);
    }
  }
}

extern "C" void kernel_launch(void* const* d_in, const int* in_sizes, int n_in,
                              void* d_out, int out_size, void* d_ws, size_t ws_size,
                              hipStream_t stream) {
  if (ws_size < WS_NEED) return;  // workspace insufficient -> deliberate clean fail
  const int*   tok = (const int*)d_in[0];
  const float* E   = (const float*)d_in[1];
  const float* Wx1 = (const float*)d_in[2];
  const float* Wh1 = (const float*)d_in[3];
  const float* bx1 = (const float*)d_in[4];
  const float* bh1 = (const float*)d_in[5];
  const float* Wx2 = (const float*)d_in[6];
  const float* Wh2 = (const float*)d_in[7];
  const float* bx2 = (const float*)d_in[8];
  const float* bh2 = (const float*)d_in[9];
  const float* Wf  = (const float*)d_in[10];
  const float* bfp = (const float*)d_in[11];
  char* ws = (char*)d_ws;
  bf16* WT   = (bf16*)(ws + WT_OFF);
  bf16* WXT  = (bf16*)(ws + WXT_OFF);
  bf16* Xg   = (bf16*)(ws + XG_OFF);
  bf16* GX1  = (bf16*)(ws + GX1_OFF);
  bf16* h0b  = (bf16*)(ws + H0B_OFF);
  bf16* h1b  = (bf16*)(ws + H1B_OFF);
  int*  cnt  = (int*)(ws + CNT_OFF);

  // zero only what's read-before-write: h0b[0], h1b[0], counters
  hipMemsetAsync(ws + H0B_OFF, 0, 262144, stream);
  hipMemsetAsync(ws + H1B_OFF, 0, 262144, stream);
  hipMemsetAsync(ws + CNT_OFF, 0, 2048, stream);
  k_embed<<<dim3(5120), dim3(256), 0, stream>>>(tok, E, Xg);
  k_trans<<<dim3(96, 32, 3), dim3(32, 8), 0, stream>>>(Wh1, Wx2, Wh2, WT);
  k_wxt<<<dim3(96, 4), dim3(32, 8), 0, stream>>>(Wx1, WXT);
  k_gx1<<<dim3(160, 48), dim3(256), 0, stream>>>(Xg, WXT, bx1, GX1);
  hipFuncSetAttribute((const void*)k_main, hipFuncAttributeMaxDynamicSharedMemorySize, LDS_BYTES);
  k_main<<<dim3(NB), dim3(NT), LDS_BYTES, stream>>>(WT, GX1, h0b, h1b, cnt,
                                                    bh1, bx2, bh2, Wf, bfp, (float*)d_out);
}